// Round 8
// baseline (84.502 us; speedup 1.0000x reference)
//
#include <hip/hip_runtime.h>
#include <hip/hip_bf16.h>

#define N_NODES 1024
#define B_SZ 64
#define F_IN 10
#define DIM 64
#define TOPK 20
#define BN_TOT (B_SZ * N_NODES)   // 65536

#define TR_BLKS 16                // emb transpose, 64-row tiles
#define PREP_BLKS 256             // inv-norms, 4 nodes/block
#define HS_BLKS 4096              // hscal, 16 nodes/block
#define K0_BLKS (TR_BLKS + PREP_BLKS + 1 + HS_BLKS)

// ---- K0: transpose + inv-norms + bnp fold + hscal (bf16 h, folded scalars) ----
__global__ __launch_bounds__(256) void k_pre(
    const float* __restrict__ data, const float* __restrict__ emb,
    const float* __restrict__ W_lin,
    const float* __restrict__ att_i, const float* __restrict__ att_j,
    const float* __restrict__ att_em_i, const float* __restrict__ att_em_j,
    const float* __restrict__ gnn_bias,
    const float* __restrict__ g1, const float* __restrict__ b1,
    const float* __restrict__ m1, const float* __restrict__ v1,
    const float* __restrict__ g2, const float* __restrict__ b2,
    const float* __restrict__ m2, const float* __restrict__ v2,
    float* __restrict__ embT, float* __restrict__ rn,
    __hip_bfloat16* __restrict__ h, float* __restrict__ ddt,
    float* __restrict__ sst, float4* __restrict__ bnp) {
    const int bid = blockIdx.x;
    const int t = threadIdx.x;
    const int lane = t & 63, w = t >> 6;

    if (bid < TR_BLKS) {
        // ---- transpose 64 rows of emb into embT[64][1024] ----
        __shared__ float T[64][65];
        const int r0 = bid * 64;
#pragma unroll
        for (int k = 0; k < 16; ++k) {
            int idx = t + k * 256;
            T[idx >> 6][idx & 63] = emb[(r0 + (idx >> 6)) * DIM + (idx & 63)];
        }
        __syncthreads();
#pragma unroll
        for (int k = 0; k < 16; ++k) {
            int idx = t + k * 256;
            int d = idx >> 6, j = idx & 63;
            embT[d * N_NODES + r0 + j] = T[j][d];
        }
        return;
    }

    if (bid < TR_BLKS + PREP_BLKS) {
        // ---- per-node inverse emb norm ----
        const int node = (bid - TR_BLKS) * 4 + w;
        float e = emb[node * DIM + lane];
        float t3 = e * e;
#pragma unroll
        for (int m = 32; m >= 1; m >>= 1) t3 += __shfl_xor(t3, m, 64);
        if (lane == 0) rn[node] = rsqrtf(t3);
        return;
    }

    if (bid == TR_BLKS + PREP_BLKS) {
        if (t < DIM) {
            float a1 = g1[t] * rsqrtf(v1[t] + 1e-5f);
            float c1 = (gnn_bias[t] - m1[t]) * a1 + b1[t];
            float a2 = g2[t] * rsqrtf(v2[t] + 1e-5f);
            float c2 = b2[t] - m2[t] * a2;
            bnp[t] = make_float4(a1, c1, a2, c2);
        }
        return;
    }

    // ---- hscal: h = x@W_lin (bf16) + fully-folded per-node att scalars ----
    {
        const int base = (bid - TR_BLKS - PREP_BLKS - 1) * 16 + w * 4;
        float wl[F_IN];
#pragma unroll
        for (int f = 0; f < F_IN; ++f) wl[f] = W_lin[f * DIM + lane];
        const float ai = att_i[lane], aj = att_j[lane];
        const float aei = att_em_i[lane], aej = att_em_j[lane];
#pragma unroll
        for (int r = 0; r < 4; ++r) {
            const int node = base + r;
            const int i = node & (N_NODES - 1);
            const float ev = emb[i * DIM + lane];
            const float* dp = data + node * F_IN;
            float hv = 0.f;
#pragma unroll
            for (int f = 0; f < F_IN; ++f) hv = fmaf(dp[f], wl[f], hv);
            h[node * DIM + lane] = __float2bfloat16(hv);
            float s1 = fmaf(hv, ai, ev * aei);
            float s2 = fmaf(hv, aj, ev * aej);
#pragma unroll
            for (int m = 32; m >= 1; m >>= 1) {
                s1 += __shfl_xor(s1, m, 64);
                s2 += __shfl_xor(s2, m, 64);
            }
            if (lane == 0) { ddt[node] = s1; sst[node] = s2; }
        }
    }
}

// ---- K1: fused cos-row + exact top-20. 1 row/block, 2 waves, no LDS in dot ----
__global__ __launch_bounds__(128) void k_gt(
    const float* __restrict__ emb, const float* __restrict__ embT,
    const float* __restrict__ rn, int* __restrict__ tk) {
    __shared__ float cv[2][20];
    __shared__ int ci[2][20];
    const int row = blockIdx.x;
    const int w = threadIdx.x >> 6, lane = threadIdx.x & 63;
    const int c0 = w * 512 + lane * 8;       // 8 consecutive cols per lane

    const float rni = rn[row];
    const float4 rc0 = *(const float4*)(rn + c0);
    const float4 rc1 = *(const float4*)(rn + c0 + 4);

    const float* __restrict__ ar = emb + row * DIM;   // uniform -> scalar loads
    float dot[8] = {};
#pragma unroll
    for (int d = 0; d < 64; ++d) {
        const float ad = ar[d];
        const float* tr = embT + d * N_NODES + c0;
        const float4 p0 = *(const float4*)tr;
        const float4 p1 = *(const float4*)(tr + 4);
        dot[0] = fmaf(ad, p0.x, dot[0]);
        dot[1] = fmaf(ad, p0.y, dot[1]);
        dot[2] = fmaf(ad, p0.z, dot[2]);
        dot[3] = fmaf(ad, p0.w, dot[3]);
        dot[4] = fmaf(ad, p1.x, dot[4]);
        dot[5] = fmaf(ad, p1.y, dot[5]);
        dot[6] = fmaf(ad, p1.z, dot[6]);
        dot[7] = fmaf(ad, p1.w, dot[7]);
    }
    float v[8];
    v[0] = dot[0] * rni * rc0.x;
    v[1] = dot[1] * rni * rc0.y;
    v[2] = dot[2] * rni * rc0.z;
    v[3] = dot[3] * rni * rc0.w;
    v[4] = dot[4] * rni * rc1.x;
    v[5] = dot[5] * rni * rc1.y;
    v[6] = dot[6] * rni * rc1.z;
    v[7] = dot[7] * rni * rc1.w;

    // phase 1: per-wave exact top-20 of its 512 cols
    for (int it = 0; it < TOPK; ++it) {
        float bv = v[0];
        int bq = 0;
#pragma unroll
        for (int q = 1; q < 8; ++q)
            if (v[q] > bv) { bv = v[q]; bq = q; }
        int bidx = c0 + bq;
#pragma unroll
        for (int m = 32; m >= 1; m >>= 1) {
            float ov = __shfl_xor(bv, m, 64);
            int oi = __shfl_xor(bidx, m, 64);
            if (ov > bv || (ov == bv && oi < bidx)) { bv = ov; bidx = oi; }
        }
        if (lane == 0) { cv[w][it] = bv; ci[w][it] = bidx; }
        if (((bidx >> 3) & 63) == lane && (bidx >> 9) == w) v[bidx & 7] = -3.0e38f;
    }
    __syncthreads();

    // phase 2: wave 0 merges 40 candidates -> exact top-20
    if (w == 0) {
        float mval = -3.0e38f;
        int midx = 0x7fffffff;
        if (lane < 2 * TOPK) { mval = cv[lane / 20][lane % 20]; midx = ci[lane / 20][lane % 20]; }
        for (int it = 0; it < TOPK; ++it) {
            float bv = mval;
            int bidx = midx;
#pragma unroll
            for (int m = 32; m >= 1; m >>= 1) {
                float ov = __shfl_xor(bv, m, 64);
                int oi = __shfl_xor(bidx, m, 64);
                if (ov > bv || (ov == bv && oi < bidx)) { bv = ov; bidx = oi; }
            }
            if (lane == 0) tk[row * TOPK + it] = bidx;
            if (midx == bidx) mval = -3.0e38f;
        }
    }
}

// ---- K2: softmax + aggregate + folded BN/head (bf16 h rows, SGPR addressing) ----
__global__ __launch_bounds__(256) void k_main(
    const __hip_bfloat16* __restrict__ h, const float* __restrict__ emb,
    const float* __restrict__ ddt, const float* __restrict__ sst,
    const int* __restrict__ tk, const float4* __restrict__ bnp,
    const float* __restrict__ outW, const float* __restrict__ outB,
    float* __restrict__ out) {
    const int bid = blockIdx.x;
    const int nb = (bid & 7) * 2048 + (bid >> 3);   // XCD swizzle
    const int w = threadIdx.x >> 6, lane = threadIdx.x & 63;
    const int node = nb * 4 + w;
    const int i = node & (N_NODES - 1);
    const int bbase = node & ~(N_NODES - 1);

    int j = i;
    if (lane < TOPK) j = tk[i * TOPK + lane];

    float sv = 0.f;
    if (lane <= TOPK) sv = sst[bbase + j];
    const float ddv = ddt[node];

    const __hip_bfloat16* hb = h + (size_t)bbase * DIM + lane;
    float hvf[TOPK + 1];
#pragma unroll
    for (int k = 0; k < TOPK; ++k) {
        int jk = __builtin_amdgcn_readlane(j, k);
        hvf[k] = __bfloat162float(hb[(size_t)jk * DIM]);
    }
    hvf[TOPK] = __bfloat162float(hb[(size_t)i * DIM]);

    const bool masked = (lane < TOPK) && (j == i);
    float lg = -3.0e38f;
    if (lane <= TOPK) {
        float l = ddv + sv;
        l = (l > 0.f) ? l : 0.2f * l;              // leaky_relu(0.2)
        lg = masked ? -3.0e38f : l;
    }
    float m = lg;
#pragma unroll
    for (int mm = 16; mm >= 1; mm >>= 1) m = fmaxf(m, __shfl_xor(m, mm, 64));
    float ex = (lane <= TOPK && !masked) ? __expf(lg - m) : 0.f;
    float s = ex;
#pragma unroll
    for (int mm = 16; mm >= 1; mm >>= 1) s += __shfl_xor(s, mm, 64);
    const float alpha = ex / s;

    float agg = 0.f;
#pragma unroll
    for (int k = 0; k <= TOPK; ++k) {
        int ab = __builtin_amdgcn_readlane(__float_as_int(alpha), k);
        agg = fmaf(__int_as_float(ab), hvf[k], agg);
    }

    const float4 p = bnp[lane];
    float x1 = fmaxf(fmaf(agg, p.x, p.y), 0.f);
    float y = x1 * emb[i * DIM + lane];
    float x2 = fmaxf(fmaf(y, p.z, p.w), 0.f);
    float o = x2 * outW[lane];
#pragma unroll
    for (int mm = 32; mm >= 1; mm >>= 1) o += __shfl_xor(o, mm, 64);
    if (lane == 0) out[node] = o + outB[0];
}

extern "C" void kernel_launch(void* const* d_in, const int* in_sizes, int n_in,
                              void* d_out, int out_size, void* d_ws, size_t ws_size,
                              hipStream_t stream) {
    const float* data     = (const float*)d_in[0];
    const float* emb      = (const float*)d_in[1];
    const float* W_lin    = (const float*)d_in[2];
    const float* att_i    = (const float*)d_in[3];
    const float* att_j    = (const float*)d_in[4];
    const float* att_em_i = (const float*)d_in[5];
    const float* att_em_j = (const float*)d_in[6];
    const float* gnn_bias = (const float*)d_in[7];
    const float* g1 = (const float*)d_in[8];
    const float* b1 = (const float*)d_in[9];
    const float* m1 = (const float*)d_in[10];
    const float* v1 = (const float*)d_in[11];
    const float* g2 = (const float*)d_in[12];
    const float* b2 = (const float*)d_in[13];
    const float* m2 = (const float*)d_in[14];
    const float* v2 = (const float*)d_in[15];
    const float* outW = (const float*)d_in[16];
    const float* outB = (const float*)d_in[17];
    float* out = (float*)d_out;

    char* ws = (char*)d_ws;
    __hip_bfloat16* h = (__hip_bfloat16*)ws;                      // 8 MB
    float* embT = (float*)(ws + ((size_t)8 << 20));               // 256 KB
    float* ddt  = embT + (size_t)DIM * N_NODES;                   // 256 KB
    float* sst  = ddt + BN_TOT;                                   // 256 KB
    float* rn   = sst + BN_TOT;                                   // 4 KB
    int*   tk   = (int*)(rn + N_NODES);                           // 80 KB
    float4* bnp = (float4*)(tk + N_NODES * TOPK);                 // 1 KB

    k_pre<<<K0_BLKS, 256, 0, stream>>>(
        data, emb, W_lin, att_i, att_j, att_em_i, att_em_j, gnn_bias,
        g1, b1, m1, v1, g2, b2, m2, v2,
        embT, rn, h, ddt, sst, bnp);
    k_gt<<<N_NODES, 128, 0, stream>>>(emb, embT, rn, tk);
    k_main<<<BN_TOT / 4, 256, 0, stream>>>(h, emb, ddt, sst, tk, bnp,
                                           outW, outB, out);
}

// Round 9
// 83.891 us; speedup vs baseline: 1.0073x; 1.0073x over previous
//
#include <hip/hip_runtime.h>
#include <hip/hip_bf16.h>

#define N_NODES 1024
#define B_SZ 64
#define F_IN 10
#define DIM 64
#define TOPK 20
#define BN_TOT (B_SZ * N_NODES)   // 65536

#define TR_BLKS 16                // emb transpose, 64-row tiles
#define PREP_BLKS 256             // inv-norms, 4 nodes/block
#define HS_BLKS 4096              // hscal, 16 nodes/block
#define K0_BLKS (TR_BLKS + PREP_BLKS + 1 + HS_BLKS)

// ---- K0: transpose + inv-norms + bnp fold + hscal (bf16 h, folded scalars) ----
__global__ __launch_bounds__(256) void k_pre(
    const float* __restrict__ data, const float* __restrict__ emb,
    const float* __restrict__ W_lin,
    const float* __restrict__ att_i, const float* __restrict__ att_j,
    const float* __restrict__ att_em_i, const float* __restrict__ att_em_j,
    const float* __restrict__ gnn_bias,
    const float* __restrict__ g1, const float* __restrict__ b1,
    const float* __restrict__ m1, const float* __restrict__ v1,
    const float* __restrict__ g2, const float* __restrict__ b2,
    const float* __restrict__ m2, const float* __restrict__ v2,
    float* __restrict__ embT, float* __restrict__ rn,
    __hip_bfloat16* __restrict__ h, float* __restrict__ ddt,
    float* __restrict__ sst, float4* __restrict__ bnp) {
    const int bid = blockIdx.x;
    const int t = threadIdx.x;
    const int lane = t & 63, w = t >> 6;

    if (bid < TR_BLKS) {
        // ---- transpose 64 rows of emb into embT[64][1024] ----
        __shared__ float T[64][65];
        const int r0 = bid * 64;
#pragma unroll
        for (int k = 0; k < 16; ++k) {
            int idx = t + k * 256;
            T[idx >> 6][idx & 63] = emb[(r0 + (idx >> 6)) * DIM + (idx & 63)];
        }
        __syncthreads();
#pragma unroll
        for (int k = 0; k < 16; ++k) {
            int idx = t + k * 256;
            int d = idx >> 6, j = idx & 63;
            embT[d * N_NODES + r0 + j] = T[j][d];
        }
        return;
    }

    if (bid < TR_BLKS + PREP_BLKS) {
        // ---- per-node inverse emb norm ----
        const int node = (bid - TR_BLKS) * 4 + w;
        float e = emb[node * DIM + lane];
        float t3 = e * e;
#pragma unroll
        for (int m = 32; m >= 1; m >>= 1) t3 += __shfl_xor(t3, m, 64);
        if (lane == 0) rn[node] = rsqrtf(t3);
        return;
    }

    if (bid == TR_BLKS + PREP_BLKS) {
        if (t < DIM) {
            float a1 = g1[t] * rsqrtf(v1[t] + 1e-5f);
            float c1 = (gnn_bias[t] - m1[t]) * a1 + b1[t];
            float a2 = g2[t] * rsqrtf(v2[t] + 1e-5f);
            float c2 = b2[t] - m2[t] * a2;
            bnp[t] = make_float4(a1, c1, a2, c2);
        }
        return;
    }

    // ---- hscal: h = x@W_lin (bf16) + fully-folded per-node att scalars ----
    {
        const int base = (bid - TR_BLKS - PREP_BLKS - 1) * 16 + w * 4;
        float wl[F_IN];
#pragma unroll
        for (int f = 0; f < F_IN; ++f) wl[f] = W_lin[f * DIM + lane];
        const float ai = att_i[lane], aj = att_j[lane];
        const float aei = att_em_i[lane], aej = att_em_j[lane];
#pragma unroll
        for (int r = 0; r < 4; ++r) {
            const int node = base + r;
            const int i = node & (N_NODES - 1);
            const float ev = emb[i * DIM + lane];
            const float* dp = data + node * F_IN;
            float hv = 0.f;
#pragma unroll
            for (int f = 0; f < F_IN; ++f) hv = fmaf(dp[f], wl[f], hv);
            h[node * DIM + lane] = __float2bfloat16(hv);
            float s1 = fmaf(hv, ai, ev * aei);
            float s2 = fmaf(hv, aj, ev * aej);
#pragma unroll
            for (int m = 32; m >= 1; m >>= 1) {
                s1 += __shfl_xor(s1, m, 64);
                s2 += __shfl_xor(s2, m, 64);
            }
            if (lane == 0) { ddt[node] = s1; sst[node] = s2; }
        }
    }
}

// ---- K1: fused cos-row + exact top-20; ALL private arrays statically indexed ----
__global__ __launch_bounds__(128) void k_gt(
    const float* __restrict__ emb, const float* __restrict__ embT,
    const float* __restrict__ rn, int* __restrict__ tk) {
    __shared__ float cv[2][20];
    __shared__ int ci[2][20];
    const int row = blockIdx.x;
    const int w = threadIdx.x >> 6, lane = threadIdx.x & 63;
    const int c0 = w * 512 + lane * 8;       // 8 consecutive cols per lane

    const float rni = rn[row];
    const float4 rc0 = *(const float4*)(rn + c0);
    const float4 rc1 = *(const float4*)(rn + c0 + 4);

    const float* __restrict__ ar = emb + row * DIM;   // uniform -> scalar loads
    float dot[8] = {};
#pragma unroll
    for (int d = 0; d < 64; ++d) {
        const float ad = ar[d];
        const float* tr = embT + d * N_NODES + c0;
        const float4 p0 = *(const float4*)tr;
        const float4 p1 = *(const float4*)(tr + 4);
        dot[0] = fmaf(ad, p0.x, dot[0]);
        dot[1] = fmaf(ad, p0.y, dot[1]);
        dot[2] = fmaf(ad, p0.z, dot[2]);
        dot[3] = fmaf(ad, p0.w, dot[3]);
        dot[4] = fmaf(ad, p1.x, dot[4]);
        dot[5] = fmaf(ad, p1.y, dot[5]);
        dot[6] = fmaf(ad, p1.z, dot[6]);
        dot[7] = fmaf(ad, p1.w, dot[7]);
    }
    float v[8];
    v[0] = dot[0] * rni * rc0.x;
    v[1] = dot[1] * rni * rc0.y;
    v[2] = dot[2] * rni * rc0.z;
    v[3] = dot[3] * rni * rc0.w;
    v[4] = dot[4] * rni * rc1.x;
    v[5] = dot[5] * rni * rc1.y;
    v[6] = dot[6] * rni * rc1.z;
    v[7] = dot[7] * rni * rc1.w;

    // phase 1: per-wave exact top-20 of its 512 cols (registers only)
    for (int it = 0; it < TOPK; ++it) {
        float bv = v[0];
        int bq = 0;
#pragma unroll
        for (int q = 1; q < 8; ++q)
            if (v[q] > bv) { bv = v[q]; bq = q; }
        int bidx = c0 + bq;
#pragma unroll
        for (int m = 32; m >= 1; m >>= 1) {
            float ov = __shfl_xor(bv, m, 64);
            int oi = __shfl_xor(bidx, m, 64);
            if (ov > bv || (ov == bv && oi < bidx)) { bv = ov; bidx = oi; }
        }
        if (lane == 0) { cv[w][it] = bv; ci[w][it] = bidx; }
        // kill the winner with STATIC indices (predicated; stays in VGPRs)
#pragma unroll
        for (int q = 0; q < 8; ++q)
            v[q] = (c0 + q == bidx) ? -3.0e38f : v[q];
    }
    __syncthreads();

    // phase 2: wave 0 merges 40 candidates -> exact top-20 (scalars only)
    if (w == 0) {
        float mval = -3.0e38f;
        int midx = 0x7fffffff;
        if (lane < 2 * TOPK) { mval = cv[lane / 20][lane % 20]; midx = ci[lane / 20][lane % 20]; }
        for (int it = 0; it < TOPK; ++it) {
            float bv = mval;
            int bidx = midx;
#pragma unroll
            for (int m = 32; m >= 1; m >>= 1) {
                float ov = __shfl_xor(bv, m, 64);
                int oi = __shfl_xor(bidx, m, 64);
                if (ov > bv || (ov == bv && oi < bidx)) { bv = ov; bidx = oi; }
            }
            if (lane == 0) tk[row * TOPK + it] = bidx;
            if (midx == bidx) mval = -3.0e38f;
        }
    }
}

// ---- K2: softmax + aggregate + folded BN/head (bf16 h rows, SGPR addressing) ----
__global__ __launch_bounds__(256) void k_main(
    const __hip_bfloat16* __restrict__ h, const float* __restrict__ emb,
    const float* __restrict__ ddt, const float* __restrict__ sst,
    const int* __restrict__ tk, const float4* __restrict__ bnp,
    const float* __restrict__ outW, const float* __restrict__ outB,
    float* __restrict__ out) {
    const int bid = blockIdx.x;
    const int nb = (bid & 7) * 2048 + (bid >> 3);   // XCD swizzle
    const int w = threadIdx.x >> 6, lane = threadIdx.x & 63;
    const int node = nb * 4 + w;
    const int i = node & (N_NODES - 1);
    const int bbase = node & ~(N_NODES - 1);

    int j = i;
    if (lane < TOPK) j = tk[i * TOPK + lane];

    float sv = 0.f;
    if (lane <= TOPK) sv = sst[bbase + j];
    const float ddv = ddt[node];

    const __hip_bfloat16* hb = h + (size_t)bbase * DIM + lane;
    float hvf[TOPK + 1];
#pragma unroll
    for (int k = 0; k < TOPK; ++k) {
        int jk = __builtin_amdgcn_readlane(j, k);
        hvf[k] = __bfloat162float(hb[(size_t)jk * DIM]);
    }
    hvf[TOPK] = __bfloat162float(hb[(size_t)i * DIM]);

    const bool masked = (lane < TOPK) && (j == i);
    float lg = -3.0e38f;
    if (lane <= TOPK) {
        float l = ddv + sv;
        l = (l > 0.f) ? l : 0.2f * l;              // leaky_relu(0.2)
        lg = masked ? -3.0e38f : l;
    }
    float m = lg;
#pragma unroll
    for (int mm = 16; mm >= 1; mm >>= 1) m = fmaxf(m, __shfl_xor(m, mm, 64));
    float ex = (lane <= TOPK && !masked) ? __expf(lg - m) : 0.f;
    float s = ex;
#pragma unroll
    for (int mm = 16; mm >= 1; mm >>= 1) s += __shfl_xor(s, mm, 64);
    const float alpha = ex / s;

    float agg = 0.f;
#pragma unroll
    for (int k = 0; k <= TOPK; ++k) {
        int ab = __builtin_amdgcn_readlane(__float_as_int(alpha), k);
        agg = fmaf(__int_as_float(ab), hvf[k], agg);
    }

    const float4 p = bnp[lane];
    float x1 = fmaxf(fmaf(agg, p.x, p.y), 0.f);
    float y = x1 * emb[i * DIM + lane];
    float x2 = fmaxf(fmaf(y, p.z, p.w), 0.f);
    float o = x2 * outW[lane];
#pragma unroll
    for (int mm = 32; mm >= 1; mm >>= 1) o += __shfl_xor(o, mm, 64);
    if (lane == 0) out[node] = o + outB[0];
}

extern "C" void kernel_launch(void* const* d_in, const int* in_sizes, int n_in,
                              void* d_out, int out_size, void* d_ws, size_t ws_size,
                              hipStream_t stream) {
    const float* data     = (const float*)d_in[0];
    const float* emb      = (const float*)d_in[1];
    const float* W_lin    = (const float*)d_in[2];
    const float* att_i    = (const float*)d_in[3];
    const float* att_j    = (const float*)d_in[4];
    const float* att_em_i = (const float*)d_in[5];
    const float* att_em_j = (const float*)d_in[6];
    const float* gnn_bias = (const float*)d_in[7];
    const float* g1 = (const float*)d_in[8];
    const float* b1 = (const float*)d_in[9];
    const float* m1 = (const float*)d_in[10];
    const float* v1 = (const float*)d_in[11];
    const float* g2 = (const float*)d_in[12];
    const float* b2 = (const float*)d_in[13];
    const float* m2 = (const float*)d_in[14];
    const float* v2 = (const float*)d_in[15];
    const float* outW = (const float*)d_in[16];
    const float* outB = (const float*)d_in[17];
    float* out = (float*)d_out;

    char* ws = (char*)d_ws;
    __hip_bfloat16* h = (__hip_bfloat16*)ws;                      // 8 MB
    float* embT = (float*)(ws + ((size_t)8 << 20));               // 256 KB
    float* ddt  = embT + (size_t)DIM * N_NODES;                   // 256 KB
    float* sst  = ddt + BN_TOT;                                   // 256 KB
    float* rn   = sst + BN_TOT;                                   // 4 KB
    int*   tk   = (int*)(rn + N_NODES);                           // 80 KB
    float4* bnp = (float4*)(tk + N_NODES * TOPK);                 // 1 KB

    k_pre<<<K0_BLKS, 256, 0, stream>>>(
        data, emb, W_lin, att_i, att_j, att_em_i, att_em_j, gnn_bias,
        g1, b1, m1, v1, g2, b2, m2, v2,
        embT, rn, h, ddt, sst, bnp);
    k_gt<<<N_NODES, 128, 0, stream>>>(emb, embT, rn, tk);
    k_main<<<BN_TOT / 4, 256, 0, stream>>>(h, emb, ddt, sst, tk, bnp,
                                           outW, outB, out);
}

// Round 10
// 79.709 us; speedup vs baseline: 1.0601x; 1.0525x over previous
//
#include <hip/hip_runtime.h>
#include <hip/hip_bf16.h>

#define N_NODES 1024
#define B_SZ 64
#define F_IN 10
#define DIM 64
#define TOPK 20
#define BN_TOT (B_SZ * N_NODES)   // 65536

#define TR_BLKS 16                // emb transpose, 64-row tiles
#define PREP_BLKS 256             // inv-norms, 4 nodes/block
#define HS_BLKS 4096              // hscal, 16 nodes/block
#define K0_BLKS (TR_BLKS + PREP_BLKS + 1 + HS_BLKS)

// ---- K0: transpose + inv-norms + bnp fold + hscal (bf16 h, folded scalars) ----
__global__ __launch_bounds__(256) void k_pre(
    const float* __restrict__ data, const float* __restrict__ emb,
    const float* __restrict__ W_lin,
    const float* __restrict__ att_i, const float* __restrict__ att_j,
    const float* __restrict__ att_em_i, const float* __restrict__ att_em_j,
    const float* __restrict__ gnn_bias,
    const float* __restrict__ g1, const float* __restrict__ b1,
    const float* __restrict__ m1, const float* __restrict__ v1,
    const float* __restrict__ g2, const float* __restrict__ b2,
    const float* __restrict__ m2, const float* __restrict__ v2,
    float* __restrict__ embT, float* __restrict__ rn,
    __hip_bfloat16* __restrict__ h, float* __restrict__ ddt,
    float* __restrict__ sst, float4* __restrict__ bnp) {
    const int bid = blockIdx.x;
    const int t = threadIdx.x;
    const int lane = t & 63, w = t >> 6;

    if (bid < TR_BLKS) {
        __shared__ float T[64][65];
        const int r0 = bid * 64;
#pragma unroll
        for (int k = 0; k < 16; ++k) {
            int idx = t + k * 256;
            T[idx >> 6][idx & 63] = emb[(r0 + (idx >> 6)) * DIM + (idx & 63)];
        }
        __syncthreads();
#pragma unroll
        for (int k = 0; k < 16; ++k) {
            int idx = t + k * 256;
            int d = idx >> 6, j = idx & 63;
            embT[d * N_NODES + r0 + j] = T[j][d];
        }
        return;
    }

    if (bid < TR_BLKS + PREP_BLKS) {
        const int node = (bid - TR_BLKS) * 4 + w;
        float e = emb[node * DIM + lane];
        float t3 = e * e;
#pragma unroll
        for (int m = 32; m >= 1; m >>= 1) t3 += __shfl_xor(t3, m, 64);
        if (lane == 0) rn[node] = rsqrtf(t3);
        return;
    }

    if (bid == TR_BLKS + PREP_BLKS) {
        if (t < DIM) {
            float a1 = g1[t] * rsqrtf(v1[t] + 1e-5f);
            float c1 = (gnn_bias[t] - m1[t]) * a1 + b1[t];
            float a2 = g2[t] * rsqrtf(v2[t] + 1e-5f);
            float c2 = b2[t] - m2[t] * a2;
            bnp[t] = make_float4(a1, c1, a2, c2);
        }
        return;
    }

    // ---- hscal: h = x@W_lin (bf16) + fully-folded per-node att scalars ----
    {
        const int base = (bid - TR_BLKS - PREP_BLKS - 1) * 16 + w * 4;
        float wl[F_IN];
#pragma unroll
        for (int f = 0; f < F_IN; ++f) wl[f] = W_lin[f * DIM + lane];
        const float ai = att_i[lane], aj = att_j[lane];
        const float aei = att_em_i[lane], aej = att_em_j[lane];
#pragma unroll
        for (int r = 0; r < 4; ++r) {
            const int node = base + r;
            const int i = node & (N_NODES - 1);
            const float ev = emb[i * DIM + lane];
            const float* dp = data + node * F_IN;
            float hv = 0.f;
#pragma unroll
            for (int f = 0; f < F_IN; ++f) hv = fmaf(dp[f], wl[f], hv);
            h[node * DIM + lane] = __float2bfloat16(hv);
            float s1 = fmaf(hv, ai, ev * aei);
            float s2 = fmaf(hv, aj, ev * aej);
#pragma unroll
            for (int m = 32; m >= 1; m >>= 1) {
                s1 += __shfl_xor(s1, m, 64);
                s2 += __shfl_xor(s2, m, 64);
            }
            if (lane == 0) { ddt[node] = s1; sst[node] = s2; }
        }
    }
}

// ---- K1: cos-row + exact top-20. 256 thr/row, batched loads (8 in flight) ----
__global__ __launch_bounds__(256) void k_gt(
    const float* __restrict__ emb, const float* __restrict__ embT,
    const float* __restrict__ rn, int* __restrict__ tk) {
    __shared__ float cv[4 * TOPK];
    __shared__ int ci[4 * TOPK];
    const int row = blockIdx.x;
    const int t = threadIdx.x;
    const int w = t >> 6, lane = t & 63;
    const int c0 = t * 4;                    // 4 consecutive cols per thread

    const float rni = rn[row];
    const float4 rc = *(const float4*)(rn + c0);
    const float* __restrict__ ar = emb + row * DIM;   // uniform -> scalar loads

    float dot[4] = {};
#pragma unroll
    for (int db = 0; db < 64; db += 8) {
        float4 p0 = *(const float4*)(embT + (db + 0) * N_NODES + c0);
        float4 p1 = *(const float4*)(embT + (db + 1) * N_NODES + c0);
        float4 p2 = *(const float4*)(embT + (db + 2) * N_NODES + c0);
        float4 p3 = *(const float4*)(embT + (db + 3) * N_NODES + c0);
        float4 p4 = *(const float4*)(embT + (db + 4) * N_NODES + c0);
        float4 p5 = *(const float4*)(embT + (db + 5) * N_NODES + c0);
        float4 p6 = *(const float4*)(embT + (db + 6) * N_NODES + c0);
        float4 p7 = *(const float4*)(embT + (db + 7) * N_NODES + c0);
        float a0 = ar[db + 0], a1 = ar[db + 1], a2 = ar[db + 2], a3 = ar[db + 3];
        float a4 = ar[db + 4], a5 = ar[db + 5], a6 = ar[db + 6], a7 = ar[db + 7];
        dot[0] = fmaf(a0, p0.x, dot[0]); dot[1] = fmaf(a0, p0.y, dot[1]);
        dot[2] = fmaf(a0, p0.z, dot[2]); dot[3] = fmaf(a0, p0.w, dot[3]);
        dot[0] = fmaf(a1, p1.x, dot[0]); dot[1] = fmaf(a1, p1.y, dot[1]);
        dot[2] = fmaf(a1, p1.z, dot[2]); dot[3] = fmaf(a1, p1.w, dot[3]);
        dot[0] = fmaf(a2, p2.x, dot[0]); dot[1] = fmaf(a2, p2.y, dot[1]);
        dot[2] = fmaf(a2, p2.z, dot[2]); dot[3] = fmaf(a2, p2.w, dot[3]);
        dot[0] = fmaf(a3, p3.x, dot[0]); dot[1] = fmaf(a3, p3.y, dot[1]);
        dot[2] = fmaf(a3, p3.z, dot[2]); dot[3] = fmaf(a3, p3.w, dot[3]);
        dot[0] = fmaf(a4, p4.x, dot[0]); dot[1] = fmaf(a4, p4.y, dot[1]);
        dot[2] = fmaf(a4, p4.z, dot[2]); dot[3] = fmaf(a4, p4.w, dot[3]);
        dot[0] = fmaf(a5, p5.x, dot[0]); dot[1] = fmaf(a5, p5.y, dot[1]);
        dot[2] = fmaf(a5, p5.z, dot[2]); dot[3] = fmaf(a5, p5.w, dot[3]);
        dot[0] = fmaf(a6, p6.x, dot[0]); dot[1] = fmaf(a6, p6.y, dot[1]);
        dot[2] = fmaf(a6, p6.z, dot[2]); dot[3] = fmaf(a6, p6.w, dot[3]);
        dot[0] = fmaf(a7, p7.x, dot[0]); dot[1] = fmaf(a7, p7.y, dot[1]);
        dot[2] = fmaf(a7, p7.z, dot[2]); dot[3] = fmaf(a7, p7.w, dot[3]);
    }
    float v0 = dot[0] * rni * rc.x;
    float v1 = dot[1] * rni * rc.y;
    float v2 = dot[2] * rni * rc.z;
    float v3 = dot[3] * rni * rc.w;

    // phase 1: per-wave exact top-20 of its 256 cols (all static regs)
    for (int it = 0; it < TOPK; ++it) {
        float bv = v0; int bq = 0;
        if (v1 > bv) { bv = v1; bq = 1; }
        if (v2 > bv) { bv = v2; bq = 2; }
        if (v3 > bv) { bv = v3; bq = 3; }
        int bidx = c0 + bq;
#pragma unroll
        for (int m = 32; m >= 1; m >>= 1) {
            float ov = __shfl_xor(bv, m, 64);
            int oi = __shfl_xor(bidx, m, 64);
            if (ov > bv || (ov == bv && oi < bidx)) { bv = ov; bidx = oi; }
        }
        if (lane == 0) { cv[w * TOPK + it] = bv; ci[w * TOPK + it] = bidx; }
        v0 = (c0 + 0 == bidx) ? -3.0e38f : v0;
        v1 = (c0 + 1 == bidx) ? -3.0e38f : v1;
        v2 = (c0 + 2 == bidx) ? -3.0e38f : v2;
        v3 = (c0 + 3 == bidx) ? -3.0e38f : v3;
    }
    __syncthreads();

    // phase 2: wave 0 merges 80 candidates (2 static regs/lane) -> top-20
    if (w == 0) {
        float m0 = cv[lane];
        int i0 = ci[lane];
        float m1 = -3.0e38f;
        int i1 = 0x7fffffff;
        if (lane < 16) { m1 = cv[64 + lane]; i1 = ci[64 + lane]; }
        for (int it = 0; it < TOPK; ++it) {
            float bv = m0; int bidx = i0;
            if (m1 > bv || (m1 == bv && i1 < bidx)) { bv = m1; bidx = i1; }
#pragma unroll
            for (int m = 32; m >= 1; m >>= 1) {
                float ov = __shfl_xor(bv, m, 64);
                int oi = __shfl_xor(bidx, m, 64);
                if (ov > bv || (ov == bv && oi < bidx)) { bv = ov; bidx = oi; }
            }
            if (lane == 0) tk[row * TOPK + it] = bidx;
            if (i0 == bidx) m0 = -3.0e38f;
            if (i1 == bidx) m1 = -3.0e38f;
        }
    }
}

// ---- K2: softmax + aggregate + folded BN/head (bf16 h rows, SGPR addressing) ----
__global__ __launch_bounds__(256) void k_main(
    const __hip_bfloat16* __restrict__ h, const float* __restrict__ emb,
    const float* __restrict__ ddt, const float* __restrict__ sst,
    const int* __restrict__ tk, const float4* __restrict__ bnp,
    const float* __restrict__ outW, const float* __restrict__ outB,
    float* __restrict__ out) {
    const int bid = blockIdx.x;
    const int nb = (bid & 7) * 2048 + (bid >> 3);   // XCD swizzle
    const int w = threadIdx.x >> 6, lane = threadIdx.x & 63;
    const int node = nb * 4 + w;
    const int i = node & (N_NODES - 1);
    const int bbase = node & ~(N_NODES - 1);

    int j = i;
    if (lane < TOPK) j = tk[i * TOPK + lane];

    float sv = 0.f;
    if (lane <= TOPK) sv = sst[bbase + j];
    const float ddv = ddt[node];

    const __hip_bfloat16* hb = h + (size_t)bbase * DIM + lane;
    float hvf[TOPK + 1];
#pragma unroll
    for (int k = 0; k < TOPK; ++k) {
        int jk = __builtin_amdgcn_readlane(j, k);
        hvf[k] = __bfloat162float(hb[(size_t)jk * DIM]);
    }
    hvf[TOPK] = __bfloat162float(hb[(size_t)i * DIM]);

    const bool masked = (lane < TOPK) && (j == i);
    float lg = -3.0e38f;
    if (lane <= TOPK) {
        float l = ddv + sv;
        l = (l > 0.f) ? l : 0.2f * l;              // leaky_relu(0.2)
        lg = masked ? -3.0e38f : l;
    }
    float m = lg;
#pragma unroll
    for (int mm = 16; mm >= 1; mm >>= 1) m = fmaxf(m, __shfl_xor(m, mm, 64));
    float ex = (lane <= TOPK && !masked) ? __expf(lg - m) : 0.f;
    float s = ex;
#pragma unroll
    for (int mm = 16; mm >= 1; mm >>= 1) s += __shfl_xor(s, mm, 64);
    const float alpha = ex / s;

    float agg = 0.f;
#pragma unroll
    for (int k = 0; k <= TOPK; ++k) {
        int ab = __builtin_amdgcn_readlane(__float_as_int(alpha), k);
        agg = fmaf(__int_as_float(ab), hvf[k], agg);
    }

    const float4 p = bnp[lane];
    float x1 = fmaxf(fmaf(agg, p.x, p.y), 0.f);
    float y = x1 * emb[i * DIM + lane];
    float x2 = fmaxf(fmaf(y, p.z, p.w), 0.f);
    float o = x2 * outW[lane];
#pragma unroll
    for (int mm = 32; mm >= 1; mm >>= 1) o += __shfl_xor(o, mm, 64);
    if (lane == 0) out[node] = o + outB[0];
}

extern "C" void kernel_launch(void* const* d_in, const int* in_sizes, int n_in,
                              void* d_out, int out_size, void* d_ws, size_t ws_size,
                              hipStream_t stream) {
    const float* data     = (const float*)d_in[0];
    const float* emb      = (const float*)d_in[1];
    const float* W_lin    = (const float*)d_in[2];
    const float* att_i    = (const float*)d_in[3];
    const float* att_j    = (const float*)d_in[4];
    const float* att_em_i = (const float*)d_in[5];
    const float* att_em_j = (const float*)d_in[6];
    const float* gnn_bias = (const float*)d_in[7];
    const float* g1 = (const float*)d_in[8];
    const float* b1 = (const float*)d_in[9];
    const float* m1 = (const float*)d_in[10];
    const float* v1 = (const float*)d_in[11];
    const float* g2 = (const float*)d_in[12];
    const float* b2 = (const float*)d_in[13];
    const float* m2 = (const float*)d_in[14];
    const float* v2 = (const float*)d_in[15];
    const float* outW = (const float*)d_in[16];
    const float* outB = (const float*)d_in[17];
    float* out = (float*)d_out;

    char* ws = (char*)d_ws;
    __hip_bfloat16* h = (__hip_bfloat16*)ws;                      // 8 MB
    float* embT = (float*)(ws + ((size_t)8 << 20));               // 256 KB
    float* ddt  = embT + (size_t)DIM * N_NODES;                   // 256 KB
    float* sst  = ddt + BN_TOT;                                   // 256 KB
    float* rn   = sst + BN_TOT;                                   // 4 KB
    int*   tk   = (int*)(rn + N_NODES);                           // 80 KB
    float4* bnp = (float4*)(tk + N_NODES * TOPK);                 // 1 KB

    k_pre<<<K0_BLKS, 256, 0, stream>>>(
        data, emb, W_lin, att_i, att_j, att_em_i, att_em_j, gnn_bias,
        g1, b1, m1, v1, g2, b2, m2, v2,
        embT, rn, h, ddt, sst, bnp);
    k_gt<<<N_NODES, 256, 0, stream>>>(emb, embT, rn, tk);
    k_main<<<BN_TOT / 4, 256, 0, stream>>>(h, emb, ddt, sst, tk, bnp,
                                           outW, outB, out);
}